// Round 2
// baseline (929.036 us; speedup 1.0000x reference)
//
#include <hip/hip_runtime.h>
#include <stdint.h>
#include <math.h>

// RFMNet forward. I/O fp32; internal compute bf16 MFMA with fp32 accum.
// Key algebraic opt: gx = gradX@(evecs@y) = (gradX@evecs)@y  -> precompute
// GXE/GYE once (34 GFLOP), per-block work becomes [4096x128]@[128x128] GEMMs.

typedef unsigned short u16;
typedef __attribute__((ext_vector_type(8))) short short8;
typedef __attribute__((ext_vector_type(8))) __bf16 bf16x8;
typedef __attribute__((ext_vector_type(4))) float f32x4;

#define B_ 4
#define V_ 4096
#define K_ 128
#define C_ 128

__device__ __forceinline__ float bf2f(u16 u) {
    union { unsigned i; float f; } v; v.i = ((unsigned)u) << 16; return v.f;
}
__device__ __forceinline__ u16 f2bf(float f) {
    union { float f; unsigned i; } v; v.f = f;
    unsigned u = v.i;
    return (u16)((u + 0x7fffu + ((u >> 16) & 1u)) >> 16);
}

__device__ __forceinline__ f32x4 mfma16(short8 a, short8 b, f32x4 c) {
    return __builtin_amdgcn_mfma_f32_16x16x32_bf16(
        __builtin_bit_cast(bf16x8, a), __builtin_bit_cast(bf16x8, b), c, 0, 0, 0);
}

__device__ __forceinline__ void gl_lds16(const u16* g, u16* l) {
    __builtin_amdgcn_global_load_lds(
        (const __attribute__((address_space(1))) unsigned*)g,
        (__attribute__((address_space(3))) unsigned*)l, 16, 0, 0);
}

// Block tile: (RT*32) rows x 128 cols, 256 threads (4 waves as 2x2).
// A: row-major bf16 [M,Kd] (pre-offset to tile row 0), Bt: row-major bf16
// [128,Kd] (=B^T). LDS: row*64 shorts, 8-short chunks at slot chunk^(row&7)
// (swizzle folded into the global SOURCE address so global_load_lds's
// uniform-base+lane*16 constraint is satisfied).
template <int RT>
__device__ __forceinline__ void gemm_core(const u16* A, int lda,
                                          const u16* Bt, int ldbt, int kIters,
                                          f32x4 (&acc)[RT][4], u16* As, u16* Bs) {
    const int tid = threadIdx.x;
    const int lane = tid & 63, wave = tid >> 6;
    const int rb = (wave >> 1) * (RT * 16), cb = (wave & 1) * 64;
    const int lrow = lane >> 3;
    const int xorc = (lane & 7) ^ lrow;   // per-lane source-chunk permutation
    const int q = lane >> 4, m = lane & 15;

    for (int kk = 0; kk < kIters; ++kk) {
        const u16* Ak = A + kk * 64 + xorc * 8;
        const u16* Bk = Bt + kk * 64 + xorc * 8;
#pragma unroll
        for (int g = 0; g < RT; ++g) {
            int rowb = wave * (RT * 8) + g * 8;
            gl_lds16(Ak + (size_t)(rowb + lrow) * lda, As + rowb * 64);
        }
#pragma unroll
        for (int g = 0; g < 4; ++g) {
            int rowb = wave * 32 + g * 8;
            gl_lds16(Bk + (size_t)(rowb + lrow) * ldbt, Bs + rowb * 64);
        }
        __syncthreads();
#pragma unroll
        for (int k0 = 0; k0 < 2; ++k0) {
            short8 a[RT], b[4];
#pragma unroll
            for (int t = 0; t < RT; ++t) {
                int row = rb + t * 16 + m;
                a[t] = *(const short8*)(As + row * 64 + ((((k0 << 2) + q) ^ (row & 7)) << 3));
            }
#pragma unroll
            for (int t = 0; t < 4; ++t) {
                int nr = cb + t * 16 + m;
                b[t] = *(const short8*)(Bs + nr * 64 + ((((k0 << 2) + q) ^ (nr & 7)) << 3));
            }
#pragma unroll
            for (int rt = 0; rt < RT; ++rt)
#pragma unroll
                for (int ct = 0; ct < 4; ++ct)
                    acc[rt][ct] = mfma16(a[rt], b[ct], acc[rt][ct]);
        }
        __syncthreads();
    }
}

// ---------------- transpose fp32 src -> bf16 dst^T ---------------------------
__global__ void k_tr32(const float* __restrict__ src, u16* __restrict__ dst,
                       int R, int C) {
    __shared__ u16 tile[64][65];
    int b = blockIdx.z;
    src += (size_t)b * R * C;
    dst += (size_t)b * R * C;
    int r0 = blockIdx.x * 64, c0 = blockIdx.y * 64;
    int t = threadIdx.x, cc = t & 63;
#pragma unroll
    for (int i = 0; i < 16; ++i) {
        int rr = (t >> 6) * 16 + i;
        int r = r0 + rr, c = c0 + cc;
        if (r < R && c < C) tile[rr][cc] = f2bf(src[(size_t)r * C + c]);
    }
    __syncthreads();
#pragma unroll
    for (int i = 0; i < 16; ++i) {
        int cc2 = (t >> 6) * 16 + i, rr2 = t & 63;
        int c = c0 + cc2, r = r0 + rr2;
        if (r < R && c < C) dst[(size_t)c * R + r] = tile[rr2][cc2];
    }
}

// ---------------- mass-scaled transpose: bf16 x -> bf16 (mass*x)^T ----------
__global__ void k_xmt(const u16* __restrict__ src, const float* __restrict__ mass,
                      u16* __restrict__ dst) {
    __shared__ u16 tile[64][65];
    int b = blockIdx.z;
    const u16* s = src + (size_t)b * V_ * C_;
    u16* d = dst + (size_t)b * V_ * C_;
    const float* ms = mass + (size_t)b * V_;
    int r0 = blockIdx.x * 64, c0 = blockIdx.y * 64;
    int t = threadIdx.x, cc = t & 63;
#pragma unroll
    for (int i = 0; i < 16; ++i) {
        int rr = (t >> 6) * 16 + i;
        int r = r0 + rr, c = c0 + cc;
        tile[rr][cc] = f2bf(bf2f(s[(size_t)r * C_ + c]) * ms[r]);
    }
    __syncthreads();
#pragma unroll
    for (int i = 0; i < 16; ++i) {
        int cc2 = (t >> 6) * 16 + i, rr2 = t & 63;
        d[(size_t)(c0 + cc2) * V_ + r0 + rr2] = tile[rr2][cc2];
    }
}

// ---------------- fp32 -> bf16 straight cast ---------------------------------
__global__ void k_cast(const float* __restrict__ src, u16* __restrict__ dst) {
    int i = blockIdx.x * 256 + threadIdx.x;   // one float4 per thread
    float4 f = ((const float4*)src)[i];
    ushort4 o;
    o.x = f2bf(f.x); o.y = f2bf(f.y); o.z = f2bf(f.z); o.w = f2bf(f.w);
    ((ushort4*)dst)[i] = o;
}

// ---------------- x = x_in @ Wf + bf  (K=16, VALU) ---------------------------
__global__ void k_init(const float* __restrict__ x_in, const float* __restrict__ Wf,
                       const float* __restrict__ bfv, float* __restrict__ x32,
                       u16* __restrict__ xb) {
    int idx = blockIdx.x * 256 + threadIdx.x;      // B*V*128
    int row = idx >> 7, c = idx & 127;
    float acc = bfv[c];
#pragma unroll
    for (int k = 0; k < 16; ++k)
        acc += x_in[row * 16 + k] * Wf[k * 128 + c];
    x32[idx] = acc;
    xb[idx] = f2bf(acc);
}

// ---------------- GXE/GYE = grad{X,Y} @ evecs  (K=4096, fp32 A) --------------
__global__ __launch_bounds__(256, 2) void k_gxe(const float* __restrict__ gradX,
                                                const float* __restrict__ gradY,
                                                const u16* __restrict__ evT,
                                                u16* __restrict__ GXE,
                                                u16* __restrict__ GYE) {
    __shared__ alignas(16) u16 As[64 * 64];
    __shared__ alignas(16) u16 Bs[128 * 64];
    int mt = blockIdx.x, b = blockIdx.y, op = blockIdx.z;
    const float* G = (op ? gradY : gradX) + (size_t)b * V_ * V_ + (size_t)mt * 64 * V_;
    const u16* Bt = evT + (size_t)b * K_ * V_;
    f32x4 acc[2][4];
#pragma unroll
    for (int i = 0; i < 2; ++i)
#pragma unroll
        for (int j = 0; j < 4; ++j) acc[i][j] = {0.f, 0.f, 0.f, 0.f};

    const int tid = threadIdx.x, lane = tid & 63, wave = tid >> 6;
    const int lrow = lane >> 3, xorc = (lane & 7) ^ lrow;
    const int q = lane >> 4, m = lane & 15;
    const int rb = (wave >> 1) * 32, cb = (wave & 1) * 64;
    const int arow = tid >> 3, achk = tid & 7;     // A staging: 32 rows x 8 chunks

    for (int kk = 0; kk < 64; ++kk) {
        // stage A (fp32 -> bf16, explicit swizzled ds_write)
#pragma unroll
        for (int h = 0; h < 2; ++h) {
            int r = arow + h * 32;
            const float* src = G + (size_t)r * V_ + kk * 64 + achk * 8;
            float4 f0 = *(const float4*)src;
            float4 f1 = *(const float4*)(src + 4);
            short8 v;
            v[0] = (short)f2bf(f0.x); v[1] = (short)f2bf(f0.y);
            v[2] = (short)f2bf(f0.z); v[3] = (short)f2bf(f0.w);
            v[4] = (short)f2bf(f1.x); v[5] = (short)f2bf(f1.y);
            v[6] = (short)f2bf(f1.z); v[7] = (short)f2bf(f1.w);
            *(short8*)(As + r * 64 + ((achk ^ (r & 7)) << 3)) = v;
        }
        // stage B (bf16 evT via global_load_lds)
        const u16* Bk = Bt + kk * 64 + xorc * 8;
#pragma unroll
        for (int g = 0; g < 4; ++g) {
            int rowb = wave * 32 + g * 8;
            gl_lds16(Bk + (size_t)(rowb + lrow) * V_, Bs + rowb * 64);
        }
        __syncthreads();
#pragma unroll
        for (int k0 = 0; k0 < 2; ++k0) {
            short8 a[2], bfr[4];
#pragma unroll
            for (int t = 0; t < 2; ++t) {
                int row = rb + t * 16 + m;
                a[t] = *(const short8*)(As + row * 64 + ((((k0 << 2) + q) ^ (row & 7)) << 3));
            }
#pragma unroll
            for (int t = 0; t < 4; ++t) {
                int nr = cb + t * 16 + m;
                bfr[t] = *(const short8*)(Bs + nr * 64 + ((((k0 << 2) + q) ^ (nr & 7)) << 3));
            }
#pragma unroll
            for (int rt = 0; rt < 2; ++rt)
#pragma unroll
                for (int ct = 0; ct < 4; ++ct)
                    acc[rt][ct] = mfma16(a[rt], bfr[ct], acc[rt][ct]);
        }
        __syncthreads();
    }
    u16* out = (op ? GYE : GXE) + (size_t)b * V_ * K_ + (size_t)mt * 64 * K_;
#pragma unroll
    for (int rt = 0; rt < 2; ++rt)
#pragma unroll
        for (int ct = 0; ct < 4; ++ct)
#pragma unroll
            for (int r = 0; r < 4; ++r)
                out[(size_t)(rb + rt * 16 + q * 4 + r) * K_ + cb + ct * 16 + m] =
                    f2bf(acc[rt][ct][r]);
}

// ---------------- x_spec partials: evecs^T @ (mass*x), K-chunked -------------
__global__ __launch_bounds__(256, 2) void k_spec(const u16* __restrict__ evT,
                                                 const u16* __restrict__ xmt,
                                                 float* __restrict__ specP) {
    __shared__ alignas(16) u16 As[128 * 64];
    __shared__ alignas(16) u16 Bs[128 * 64];
    int chunk = blockIdx.x, b = blockIdx.y;
    const u16* A = evT + (size_t)b * K_ * V_ + chunk * 128;
    const u16* Bt = xmt + (size_t)b * C_ * V_ + chunk * 128;
    f32x4 acc[4][4];
#pragma unroll
    for (int i = 0; i < 4; ++i)
#pragma unroll
        for (int j = 0; j < 4; ++j) acc[i][j] = {0.f, 0.f, 0.f, 0.f};
    gemm_core<4>(A, V_, Bt, V_, 2, acc, As, Bs);
    float* out = specP + (size_t)(b * 32 + chunk) * K_ * C_;
    int lane = threadIdx.x & 63, wave = threadIdx.x >> 6;
    int rb = (wave >> 1) * 64, cb = (wave & 1) * 64, q = lane >> 4, m = lane & 15;
#pragma unroll
    for (int rt = 0; rt < 4; ++rt)
#pragma unroll
        for (int ct = 0; ct < 4; ++ct)
#pragma unroll
            for (int r = 0; r < 4; ++r)
                out[(size_t)(rb + rt * 16 + q * 4 + r) * C_ + cb + ct * 16 + m] =
                    acc[rt][ct][r];
}

// ---------------- reduce partials, apply exp(-evals*t), write y^T ------------
__global__ void k_reduce(const float* __restrict__ specP,
                         const float* __restrict__ evals,
                         const float* __restrict__ tvec, u16* __restrict__ yt) {
    int idx = blockIdx.x * 256 + threadIdx.x;  // B*K*C
    int c = idx & 127, k = (idx >> 7) & 127, b = idx >> 14;
    float ti = fmaxf(tvec[c], 1e-8f);
    float ev = evals[b * 128 + k];
    float coef = expf(-ev * ti);
    float s = 0.f;
    const float* p = specP + (size_t)b * 32 * K_ * C_ + k * C_ + c;
#pragma unroll
    for (int j = 0; j < 32; ++j) s += p[(size_t)j * K_ * C_];
    yt[((size_t)b * C_ + c) * K_ + k] = f2bf(coef * s);
}

// ---------------- x_diff / gx / gy = {evecs,GXE,GYE} @ y ---------------------
__global__ __launch_bounds__(256, 2) void k_three(
    const u16* __restrict__ evb, const u16* __restrict__ gxe,
    const u16* __restrict__ gye, const u16* __restrict__ yt,
    u16* __restrict__ xd, u16* __restrict__ gx, u16* __restrict__ gy) {
    __shared__ alignas(16) u16 As[128 * 64];
    __shared__ alignas(16) u16 Bs[128 * 64];
    int mt = blockIdx.x, b = blockIdx.y, op = blockIdx.z;
    const u16* Asrc = (op == 0) ? evb : (op == 1) ? gxe : gye;
    u16* out = (op == 0) ? xd : (op == 1) ? gx : gy;
    const u16* A = Asrc + (size_t)b * V_ * K_ + (size_t)mt * 128 * K_;
    const u16* Bt = yt + (size_t)b * C_ * K_;
    f32x4 acc[4][4];
#pragma unroll
    for (int i = 0; i < 4; ++i)
#pragma unroll
        for (int j = 0; j < 4; ++j) acc[i][j] = {0.f, 0.f, 0.f, 0.f};
    gemm_core<4>(A, K_, Bt, K_, 2, acc, As, Bs);
    out += (size_t)b * V_ * C_ + (size_t)mt * 128 * C_;
    int lane = threadIdx.x & 63, wave = threadIdx.x >> 6;
    int rb = (wave >> 1) * 64, cb = (wave & 1) * 64, q = lane >> 4, m = lane & 15;
#pragma unroll
    for (int rt = 0; rt < 4; ++rt)
#pragma unroll
        for (int ct = 0; ct < 4; ++ct)
#pragma unroll
            for (int r = 0; r < 4; ++r)
                out[(size_t)(rb + rt * 16 + q * 4 + r) * C_ + cb + ct * 16 + m] =
                    f2bf(acc[rt][ct][r]);
}

// ---------------- complex-linear + tanh gradient features --------------------
// br = gx@Are - gy@Aim ; bi = gy@Are + gx@Aim ; gf = tanh(gx*br + gy*bi)
__global__ __launch_bounds__(256, 2) void k_complex(
    const u16* __restrict__ gx, const u16* __restrict__ gy,
    const u16* __restrict__ art, const u16* __restrict__ ait,
    u16* __restrict__ gf) {
    __shared__ alignas(16) u16 gxs[128 * 64];
    __shared__ alignas(16) u16 gys[128 * 64];
    __shared__ alignas(16) u16 ars[64 * 64];
    __shared__ alignas(16) u16 ais[64 * 64];
    int mt = blockIdx.x, nh = blockIdx.y, b = blockIdx.z;
    size_t boff = (size_t)b * V_ * C_ + (size_t)mt * 128 * C_;
    const int tid = threadIdx.x, lane = tid & 63, wave = tid >> 6;
    const int lrow = lane >> 3, xorc = (lane & 7) ^ lrow;
    const int q = lane >> 4, m = lane & 15;
    const int rb = wave * 32;

    f32x4 abr[2][4], abi[2][4];
#pragma unroll
    for (int i = 0; i < 2; ++i)
#pragma unroll
        for (int j = 0; j < 4; ++j) {
            abr[i][j] = {0.f, 0.f, 0.f, 0.f};
            abi[i][j] = {0.f, 0.f, 0.f, 0.f};
        }

    for (int kk = 0; kk < 2; ++kk) {
        int kof = kk * 64 + xorc * 8;
#pragma unroll
        for (int g = 0; g < 4; ++g) {
            int rowb = wave * 32 + g * 8;
            gl_lds16(gx + boff + (size_t)(rowb + lrow) * C_ + kof, gxs + rowb * 64);
            gl_lds16(gy + boff + (size_t)(rowb + lrow) * C_ + kof, gys + rowb * 64);
        }
#pragma unroll
        for (int g = 0; g < 2; ++g) {
            int rowb = wave * 16 + g * 8;
            gl_lds16(art + (size_t)(nh * 64 + rowb + lrow) * C_ + kof, ars + rowb * 64);
            gl_lds16(ait + (size_t)(nh * 64 + rowb + lrow) * C_ + kof, ais + rowb * 64);
        }
        __syncthreads();
#pragma unroll
        for (int k0 = 0; k0 < 2; ++k0) {
            short8 ax[2], ay[2], bre[4], bim[4], bimn[4];
#pragma unroll
            for (int t = 0; t < 2; ++t) {
                int row = rb + t * 16 + m;
                int off = row * 64 + ((((k0 << 2) + q) ^ (row & 7)) << 3);
                ax[t] = *(const short8*)(gxs + off);
                ay[t] = *(const short8*)(gys + off);
            }
#pragma unroll
            for (int t = 0; t < 4; ++t) {
                int nr = t * 16 + m;
                int off = nr * 64 + ((((k0 << 2) + q) ^ (nr & 7)) << 3);
                bre[t] = *(const short8*)(ars + off);
                bim[t] = *(const short8*)(ais + off);
#pragma unroll
                for (int j = 0; j < 8; ++j) bimn[t][j] = bim[t][j] ^ (short)0x8000;
            }
#pragma unroll
            for (int rt = 0; rt < 2; ++rt)
#pragma unroll
                for (int ct = 0; ct < 4; ++ct) {
                    abr[rt][ct] = mfma16(ax[rt], bre[ct], abr[rt][ct]);
                    abr[rt][ct] = mfma16(ay[rt], bimn[ct], abr[rt][ct]);
                    abi[rt][ct] = mfma16(ay[rt], bre[ct], abi[rt][ct]);
                    abi[rt][ct] = mfma16(ax[rt], bim[ct], abi[rt][ct]);
                }
        }
        __syncthreads();
    }
#pragma unroll
    for (int rt = 0; rt < 2; ++rt)
#pragma unroll
        for (int ct = 0; ct < 4; ++ct)
#pragma unroll
            for (int r = 0; r < 4; ++r) {
                int row = rb + rt * 16 + q * 4 + r;
                int col = nh * 64 + ct * 16 + m;
                size_t idx = boff + (size_t)row * C_ + col;
                float g1 = bf2f(gx[idx]), g2 = bf2f(gy[idx]);
                float z = g1 * abr[rt][ct][r] + g2 * abi[rt][ct][r];
                gf[idx] = f2bf(tanhf(z));
            }
}

// ---------------- fused 3-layer MLP + residual -------------------------------
__device__ __forceinline__ void write_h(const f32x4 (&acc)[4][4],
                                        const float* bias, u16* hb) {
    int lane = threadIdx.x & 63, wave = threadIdx.x >> 6;
    int rb = (wave >> 1) * 64, cb = (wave & 1) * 64, q = lane >> 4, m = lane & 15;
#pragma unroll
    for (int rt = 0; rt < 4; ++rt)
#pragma unroll
        for (int ct = 0; ct < 4; ++ct)
#pragma unroll
            for (int r = 0; r < 4; ++r) {
                int row = rb + rt * 16 + q * 4 + r;
                int col = cb + ct * 16 + m;
                float v = acc[rt][ct][r] + bias[col];
                v = fmaxf(v, 0.f);
                int w = col >> 6, cl = col & 63;
                hb[w * 8192 + row * 64 + (((cl >> 3) ^ (row & 7)) << 3) + (cl & 7)] =
                    f2bf(v);
            }
}

__device__ __forceinline__ void dense_lds(const u16* hb, const u16* wt,
                                          f32x4 (&acc)[4][4]) {
    int lane = threadIdx.x & 63, wave = threadIdx.x >> 6;
    int rb = (wave >> 1) * 64, cb = (wave & 1) * 64, q = lane >> 4, m = lane & 15;
#pragma unroll
    for (int k0 = 0; k0 < 4; ++k0) {
        int k = k0 * 32 + q * 8;
        int w = k >> 6, cw = (k & 63) >> 3;
        short8 a[4], bb[4];
#pragma unroll
        for (int t = 0; t < 4; ++t) {
            int row = rb + t * 16 + m;
            a[t] = *(const short8*)(hb + w * 8192 + row * 64 + ((cw ^ (row & 7)) << 3));
            int nr = cb + t * 16 + m;
            bb[t] = *(const short8*)(wt + (size_t)nr * C_ + k);
        }
#pragma unroll
        for (int rt = 0; rt < 4; ++rt)
#pragma unroll
            for (int ct = 0; ct < 4; ++ct)
                acc[rt][ct] = mfma16(a[rt], bb[ct], acc[rt][ct]);
    }
}

__global__ __launch_bounds__(256, 2) void k_mlp(
    const u16* xb, const u16* xd, const u16* gfi, const u16* w0t,
    const u16* w1t, const u16* w2t, const float* b0, const float* b1,
    const float* b2, float* x32, u16* xbw) {
    __shared__ alignas(16) u16 smem[32768];  // 64 KiB
    u16* As = smem;
    u16* Bs = smem + 8192;
    u16* h0 = smem + 16384;  // 128x128 swizzled (two 64-col windows)
    int mt = blockIdx.x, b = blockIdx.y;
    size_t boff = (size_t)b * V_ * C_ + (size_t)mt * 128 * C_;

    f32x4 acc[4][4];
#pragma unroll
    for (int i = 0; i < 4; ++i)
#pragma unroll
        for (int j = 0; j < 4; ++j) acc[i][j] = {0.f, 0.f, 0.f, 0.f};
    gemm_core<4>(xb + boff, C_, w0t, 384, 2, acc, As, Bs);
    gemm_core<4>(xd + boff, C_, w0t + 128, 384, 2, acc, As, Bs);
    gemm_core<4>(gfi + boff, C_, w0t + 256, 384, 2, acc, As, Bs);
    write_h(acc, b0, h0);
    __syncthreads();

    f32x4 acc2[4][4];
#pragma unroll
    for (int i = 0; i < 4; ++i)
#pragma unroll
        for (int j = 0; j < 4; ++j) acc2[i][j] = {0.f, 0.f, 0.f, 0.f};
    dense_lds(h0, w1t, acc2);
    u16* h1 = smem;  // overlay As/Bs (disjoint from h0)
    write_h(acc2, b1, h1);
    __syncthreads();

    f32x4 acc3[4][4];
#pragma unroll
    for (int i = 0; i < 4; ++i)
#pragma unroll
        for (int j = 0; j < 4; ++j) acc3[i][j] = {0.f, 0.f, 0.f, 0.f};
    dense_lds(h1, w2t, acc3);

    int lane = threadIdx.x & 63, wave = threadIdx.x >> 6;
    int rb = (wave >> 1) * 64, cb = (wave & 1) * 64, q = lane >> 4, m = lane & 15;
#pragma unroll
    for (int rt = 0; rt < 4; ++rt)
#pragma unroll
        for (int ct = 0; ct < 4; ++ct)
#pragma unroll
            for (int r = 0; r < 4; ++r) {
                int row = rb + rt * 16 + q * 4 + r;
                int col = cb + ct * 16 + m;
                size_t idx = boff + (size_t)row * C_ + col;
                float v = x32[idx] + acc3[rt][ct][r] + b2[col];
                x32[idx] = v;
                xbw[idx] = f2bf(v);
            }
}

// ---------------- final projection out = x @ Wl + bl (fp32 out) --------------
__global__ __launch_bounds__(256, 2) void k_final(const u16* __restrict__ xb,
                                                  const u16* __restrict__ wlt,
                                                  const float* __restrict__ bl,
                                                  float* __restrict__ out) {
    __shared__ alignas(16) u16 As[128 * 64];
    __shared__ alignas(16) u16 Bs[128 * 64];
    int mt = blockIdx.x, b = blockIdx.y;
    size_t boff = (size_t)b * V_ * C_ + (size_t)mt * 128 * C_;
    f32x4 acc[4][4];
#pragma unroll
    for (int i = 0; i < 4; ++i)
#pragma unroll
        for (int j = 0; j < 4; ++j) acc[i][j] = {0.f, 0.f, 0.f, 0.f};
    gemm_core<4>(xb + boff, C_, wlt, C_, 2, acc, As, Bs);
    int lane = threadIdx.x & 63, wave = threadIdx.x >> 6;
    int rb = (wave >> 1) * 64, cb = (wave & 1) * 64, q = lane >> 4, m = lane & 15;
#pragma unroll
    for (int rt = 0; rt < 4; ++rt)
#pragma unroll
        for (int ct = 0; ct < 4; ++ct)
#pragma unroll
            for (int r = 0; r < 4; ++r) {
                int row = rb + rt * 16 + q * 4 + r;
                int col = cb + ct * 16 + m;
                out[boff + (size_t)row * C_ + col] = acc[rt][ct][r] + bl[col];
            }
}

extern "C" void kernel_launch(void* const* d_in, const int* in_sizes, int n_in,
                              void* d_out, int out_size, void* d_ws,
                              size_t ws_size, hipStream_t stream) {
    (void)in_sizes; (void)n_in; (void)out_size; (void)ws_size;
    const float* x_in  = (const float*)d_in[0];
    const float* mass  = (const float*)d_in[1];
    const float* evals = (const float*)d_in[2];
    const float* evecs = (const float*)d_in[3];
    const float* gradX = (const float*)d_in[4];
    const float* gradY = (const float*)d_in[5];
    const float* Wf    = (const float*)d_in[6];
    const float* bfv   = (const float*)d_in[7];
    const float* Wl    = (const float*)d_in[8];
    const float* bl    = (const float*)d_in[9];
    const float* tv    = (const float*)d_in[10];
    const float* Are   = (const float*)d_in[11];
    const float* Aim   = (const float*)d_in[12];
    const float* W0    = (const float*)d_in[13];
    const float* b0    = (const float*)d_in[14];
    const float* W1    = (const float*)d_in[15];
    const float* b1    = (const float*)d_in[16];
    const float* W2    = (const float*)d_in[17];
    const float* b2    = (const float*)d_in[18];
    float* out = (float*)d_out;

    char* wsb = (char*)d_ws;
    size_t o = 0;
    auto take = [&](size_t bytes) -> void* {
        void* p = wsb + o;
        o += (bytes + 255) & ~(size_t)255;
        return p;
    };
    float* X32 = (float*)take((size_t)B_ * V_ * C_ * 4);
    u16* XB    = (u16*)take((size_t)B_ * V_ * C_ * 2);
    u16* XMT   = (u16*)take((size_t)B_ * V_ * C_ * 2);
    u16* EVT   = (u16*)take((size_t)B_ * V_ * K_ * 2);
    u16* EVB   = (u16*)take((size_t)B_ * V_ * K_ * 2);
    u16* GXE   = (u16*)take((size_t)B_ * V_ * K_ * 2);
    u16* GYE   = (u16*)take((size_t)B_ * V_ * K_ * 2);
    float* SP  = (float*)take((size_t)B_ * 32 * K_ * C_ * 4);
    u16* YT    = (u16*)take((size_t)B_ * K_ * C_ * 2);
    u16* XD    = (u16*)take((size_t)B_ * V_ * C_ * 2);
    u16* GX    = (u16*)take((size_t)B_ * V_ * C_ * 2);
    u16* GY    = (u16*)take((size_t)B_ * V_ * C_ * 2);
    u16* GF    = (u16*)take((size_t)B_ * V_ * C_ * 2);
    u16* ART   = (u16*)take((size_t)4 * C_ * C_ * 2);
    u16* AIT   = (u16*)take((size_t)4 * C_ * C_ * 2);
    u16* W0T   = (u16*)take((size_t)4 * 384 * C_ * 2);
    u16* W1T   = (u16*)take((size_t)4 * C_ * C_ * 2);
    u16* W2T   = (u16*)take((size_t)4 * C_ * C_ * 2);
    u16* WLT   = (u16*)take((size_t)C_ * C_ * 2);

    // one-time: weight / basis transposes + casts, x init, GXE/GYE
    k_tr32<<<dim3(2, 2, 4), 256, 0, stream>>>(Are, ART, 128, 128);
    k_tr32<<<dim3(2, 2, 4), 256, 0, stream>>>(Aim, AIT, 128, 128);
    k_tr32<<<dim3(6, 2, 4), 256, 0, stream>>>(W0, W0T, 384, 128);
    k_tr32<<<dim3(2, 2, 4), 256, 0, stream>>>(W1, W1T, 128, 128);
    k_tr32<<<dim3(2, 2, 4), 256, 0, stream>>>(W2, W2T, 128, 128);
    k_tr32<<<dim3(2, 2, 1), 256, 0, stream>>>(Wl, WLT, 128, 128);
    k_tr32<<<dim3(64, 2, 4), 256, 0, stream>>>(evecs, EVT, 4096, 128);
    k_cast<<<dim3(2048), 256, 0, stream>>>(evecs, EVB);
    k_init<<<dim3(8192), 256, 0, stream>>>(x_in, Wf, bfv, X32, XB);
    k_gxe<<<dim3(64, 4, 2), 256, 0, stream>>>(gradX, gradY, EVT, GXE, GYE);

    for (int i = 0; i < 4; ++i) {
        k_xmt<<<dim3(64, 2, 4), 256, 0, stream>>>(XB, mass, XMT);
        k_spec<<<dim3(32, 4), 256, 0, stream>>>(EVT, XMT, SP);
        k_reduce<<<dim3(256), 256, 0, stream>>>(SP, evals, tv + i * 128, YT);
        k_three<<<dim3(32, 4, 3), 256, 0, stream>>>(EVB, GXE, GYE, YT, XD, GX, GY);
        k_complex<<<dim3(32, 2, 4), 256, 0, stream>>>(GX, GY, ART + i * 16384,
                                                      AIT + i * 16384, GF);
        k_mlp<<<dim3(32, 4), 256, 0, stream>>>(XB, XD, GF, W0T + i * 49152,
                                               W1T + i * 16384, W2T + i * 16384,
                                               b0 + i * 128, b1 + i * 128,
                                               b2 + i * 128, X32, XB);
    }
    k_final<<<dim3(32, 4), 256, 0, stream>>>(XB, WLT, bl, out);
}

// Round 3
// 805.919 us; speedup vs baseline: 1.1528x; 1.1528x over previous
//
#include <hip/hip_runtime.h>
#include <stdint.h>
#include <math.h>

// RFMNet forward. I/O fp32; internal bf16 MFMA with fp32 accum.
// R3: k_gxe K-split (latency->BW bound), loop body fused into k_tile,
// launch count 35 -> 18.

typedef unsigned short u16;
typedef __attribute__((ext_vector_type(8))) short short8;
typedef __attribute__((ext_vector_type(8))) __bf16 bf16x8;
typedef __attribute__((ext_vector_type(4))) float f32x4;

#define B_ 4
#define V_ 4096
#define K_ 128
#define C_ 128

__device__ __forceinline__ float bf2f(u16 u) {
    union { unsigned i; float f; } v; v.i = ((unsigned)u) << 16; return v.f;
}
__device__ __forceinline__ u16 f2bf(float f) {
    union { float f; unsigned i; } v; v.f = f;
    unsigned u = v.i;
    return (u16)((u + 0x7fffu + ((u >> 16) & 1u)) >> 16);
}
__device__ __forceinline__ f32x4 mfma16(short8 a, short8 b, f32x4 c) {
    return __builtin_amdgcn_mfma_f32_16x16x32_bf16(
        __builtin_bit_cast(bf16x8, a), __builtin_bit_cast(bf16x8, b), c, 0, 0, 0);
}
__device__ __forceinline__ void gl_lds16(const u16* g, u16* l) {
    __builtin_amdgcn_global_load_lds(
        (const __attribute__((address_space(1))) unsigned*)g,
        (__attribute__((address_space(3))) unsigned*)l, 16, 0, 0);
}
// swizzled 128-el-row panel: offset of (row, col)
__device__ __forceinline__ int poff(int row, int col) {
    return row * 128 + ((col >> 6) << 6) +
           ((((col >> 3) & 7) ^ (row & 7)) << 3) + (col & 7);
}

// ---- generic 128-wide GEMM core (used by k_final) ---------------------------
template <int RT>
__device__ __forceinline__ void gemm_core(const u16* A, int lda,
                                          const u16* Bt, int ldbt, int kIters,
                                          f32x4 (&acc)[RT][4], u16* As, u16* Bs) {
    const int tid = threadIdx.x;
    const int lane = tid & 63, wave = tid >> 6;
    const int rb = (wave >> 1) * (RT * 16), cb = (wave & 1) * 64;
    const int lrow = lane >> 3;
    const int xorc = (lane & 7) ^ lrow;
    const int q = lane >> 4, m = lane & 15;
    for (int kk = 0; kk < kIters; ++kk) {
        const u16* Ak = A + kk * 64 + xorc * 8;
        const u16* Bk = Bt + kk * 64 + xorc * 8;
#pragma unroll
        for (int g = 0; g < RT; ++g) {
            int rowb = wave * (RT * 8) + g * 8;
            gl_lds16(Ak + (size_t)(rowb + lrow) * lda, As + rowb * 64);
        }
#pragma unroll
        for (int g = 0; g < 4; ++g) {
            int rowb = wave * 32 + g * 8;
            gl_lds16(Bk + (size_t)(rowb + lrow) * ldbt, Bs + rowb * 64);
        }
        __syncthreads();
#pragma unroll
        for (int k0 = 0; k0 < 2; ++k0) {
            short8 a[RT], b[4];
#pragma unroll
            for (int t = 0; t < RT; ++t) {
                int row = rb + t * 16 + m;
                a[t] = *(const short8*)(As + row * 64 + ((((k0 << 2) + q) ^ (row & 7)) << 3));
            }
#pragma unroll
            for (int t = 0; t < 4; ++t) {
                int nr = cb + t * 16 + m;
                b[t] = *(const short8*)(Bs + nr * 64 + ((((k0 << 2) + q) ^ (nr & 7)) << 3));
            }
#pragma unroll
            for (int rt = 0; rt < RT; ++rt)
#pragma unroll
                for (int ct = 0; ct < 4; ++ct)
                    acc[rt][ct] = mfma16(a[rt], b[ct], acc[rt][ct]);
        }
        __syncthreads();
    }
}

// ---- k_prep: all small weight transposes (fp32 -> bf16^T) in one launch -----
__global__ void k_prep(const float* __restrict__ Are, const float* __restrict__ Aim,
                       const float* __restrict__ W0, const float* __restrict__ W1,
                       const float* __restrict__ W2, const float* __restrict__ Wl,
                       u16* ART, u16* AIT, u16* W0T, u16* W1T, u16* W2T, u16* WLT) {
    __shared__ u16 tile[64][65];
    int id = blockIdx.x;
    const float* src; u16* dst; int R, bi2, tr, tc;
    if (id < 16)       { src = Are; dst = ART; R = 128; bi2 = id >> 2; tr = (id >> 1) & 1; tc = id & 1; }
    else if (id < 32)  { id -= 16; src = Aim; dst = AIT; R = 128; bi2 = id >> 2; tr = (id >> 1) & 1; tc = id & 1; }
    else if (id < 80)  { id -= 32; src = W0; dst = W0T; R = 384; bi2 = id / 12; int t2 = id % 12; tr = t2 >> 1; tc = t2 & 1; }
    else if (id < 96)  { id -= 80; src = W1; dst = W1T; R = 128; bi2 = id >> 2; tr = (id >> 1) & 1; tc = id & 1; }
    else if (id < 112) { id -= 96; src = W2; dst = W2T; R = 128; bi2 = id >> 2; tr = (id >> 1) & 1; tc = id & 1; }
    else               { id -= 112; src = Wl; dst = WLT; R = 128; bi2 = 0; tr = (id >> 1) & 1; tc = id & 1; }
    src += (size_t)bi2 * R * 128;
    dst += (size_t)bi2 * R * 128;
    int r0 = tr * 64, c0 = tc * 64;
    int t = threadIdx.x, cc = t & 63;
#pragma unroll
    for (int i = 0; i < 16; ++i) {
        int rr = (t >> 6) * 16 + i;
        tile[rr][cc] = f2bf(src[(size_t)(r0 + rr) * 128 + c0 + cc]);
    }
    __syncthreads();
#pragma unroll
    for (int i = 0; i < 16; ++i) {
        int cc2 = (t >> 6) * 16 + i, rr2 = t & 63;
        dst[(size_t)(c0 + cc2) * R + r0 + rr2] = tile[rr2][cc2];
    }
}

// ---- k_evt: evecs fp32 -> EVT (bf16 transposed) + EVB (bf16 cast) -----------
__global__ void k_evt(const float* __restrict__ src, u16* __restrict__ evt,
                      u16* __restrict__ evb) {
    __shared__ u16 tile[64][65];
    int bz = blockIdx.z;
    const float* s = src + (size_t)bz * V_ * K_;
    u16* dT = evt + (size_t)bz * V_ * K_;
    u16* dC = evb + (size_t)bz * V_ * K_;
    int r0 = blockIdx.x * 64, c0 = blockIdx.y * 64;
    int t = threadIdx.x, cc = t & 63;
#pragma unroll
    for (int i = 0; i < 16; ++i) {
        int rr = (t >> 6) * 16 + i;
        int r = r0 + rr, c = c0 + cc;
        u16 u = f2bf(s[(size_t)r * K_ + c]);
        tile[rr][cc] = u;
        dC[(size_t)r * K_ + c] = u;
    }
    __syncthreads();
#pragma unroll
    for (int i = 0; i < 16; ++i) {
        int cc2 = (t >> 6) * 16 + i, rr2 = t & 63;
        dT[(size_t)(c0 + cc2) * V_ + r0 + rr2] = tile[rr2][cc2];
    }
}

// ---- k_init: x = x_in @ Wf + bf  (K=16, VALU) -------------------------------
__global__ void k_init(const float* __restrict__ x_in, const float* __restrict__ Wf,
                       const float* __restrict__ bfv, float* __restrict__ x32,
                       u16* __restrict__ xb) {
    int idx = blockIdx.x * 256 + threadIdx.x;   // B*V*128
    int row = idx >> 7, c = idx & 127;
    float acc = bfv[c];
#pragma unroll
    for (int k = 0; k < 16; ++k)
        acc += x_in[row * 16 + k] * Wf[k * 128 + c];
    x32[idx] = acc;
    xb[idx] = f2bf(acc);
}

// ---- k_gxe: partial grad{X,Y}@evecs, K-split x4, fp32 partials --------------
__global__ __launch_bounds__(256, 2) void k_gxe(const float* __restrict__ gX,
                                                const float* __restrict__ gY,
                                                const u16* __restrict__ evT,
                                                float* __restrict__ GP) {
    __shared__ alignas(16) u16 As[64 * 64];
    __shared__ alignas(16) u16 Bs[128 * 64];
    int mt = blockIdx.x, ks = blockIdx.y, z = blockIdx.z;  // z = op*4 + b
    int op = z >> 2, b = z & 3;
    const float* G = (op ? gY : gX) + (size_t)b * V_ * V_ + (size_t)mt * 64 * V_ + ks * 1024;
    const u16* Bt = evT + (size_t)b * K_ * V_ + ks * 1024;
    f32x4 acc[2][4];
#pragma unroll
    for (int i = 0; i < 2; ++i)
#pragma unroll
        for (int j = 0; j < 4; ++j) acc[i][j] = {0.f, 0.f, 0.f, 0.f};

    const int tid = threadIdx.x, lane = tid & 63, wave = tid >> 6;
    const int lrow = lane >> 3, xorc = (lane & 7) ^ lrow;
    const int q = lane >> 4, m = lane & 15;
    const int rb = (wave >> 1) * 32, cb = (wave & 1) * 64;
    const int arow = tid >> 3, achk = tid & 7;

    for (int kk = 0; kk < 16; ++kk) {
#pragma unroll
        for (int h = 0; h < 2; ++h) {
            int r = arow + h * 32;
            const float* src = G + (size_t)r * V_ + kk * 64 + achk * 8;
            float4 f0 = *(const float4*)src;
            float4 f1 = *(const float4*)(src + 4);
            short8 v;
            v[0] = (short)f2bf(f0.x); v[1] = (short)f2bf(f0.y);
            v[2] = (short)f2bf(f0.z); v[3] = (short)f2bf(f0.w);
            v[4] = (short)f2bf(f1.x); v[5] = (short)f2bf(f1.y);
            v[6] = (short)f2bf(f1.z); v[7] = (short)f2bf(f1.w);
            *(short8*)(As + r * 64 + ((achk ^ (r & 7)) << 3)) = v;
        }
        const u16* Bk = Bt + kk * 64 + xorc * 8;
#pragma unroll
        for (int g = 0; g < 4; ++g) {
            int rowb = wave * 32 + g * 8;
            gl_lds16(Bk + (size_t)(rowb + lrow) * V_, Bs + rowb * 64);
        }
        __syncthreads();
#pragma unroll
        for (int k0 = 0; k0 < 2; ++k0) {
            short8 a[2], bfr[4];
#pragma unroll
            for (int t = 0; t < 2; ++t) {
                int row = rb + t * 16 + m;
                a[t] = *(const short8*)(As + row * 64 + ((((k0 << 2) + q) ^ (row & 7)) << 3));
            }
#pragma unroll
            for (int t = 0; t < 4; ++t) {
                int nr = cb + t * 16 + m;
                bfr[t] = *(const short8*)(Bs + nr * 64 + ((((k0 << 2) + q) ^ (nr & 7)) << 3));
            }
#pragma unroll
            for (int rt = 0; rt < 2; ++rt)
#pragma unroll
                for (int ct = 0; ct < 4; ++ct)
                    acc[rt][ct] = mfma16(a[rt], bfr[ct], acc[rt][ct]);
        }
        __syncthreads();
    }
    float* out = GP + ((size_t)z * 4 + ks) * ((size_t)V_ * K_) + (size_t)mt * 64 * K_;
#pragma unroll
    for (int rt = 0; rt < 2; ++rt)
#pragma unroll
        for (int ct = 0; ct < 4; ++ct)
#pragma unroll
            for (int r = 0; r < 4; ++r)
                out[(size_t)(rb + rt * 16 + q * 4 + r) * K_ + cb + ct * 16 + m] =
                    acc[rt][ct][r];
}

// ---- k_gxered: sum 4 K-split partials -> bf16 GXE/GYE -----------------------
__global__ void k_gxered(const float* __restrict__ GP, u16* __restrict__ GXE,
                         u16* __restrict__ GYE) {
    int i = blockIdx.x * 256 + threadIdx.x;      // over (8*V*K)/4
    size_t e = (size_t)i * 4;
    int z = (int)(e / ((size_t)V_ * K_));
    size_t r = e - (size_t)z * V_ * K_;
    const float* base = GP + (size_t)z * 4 * V_ * K_ + r;
    float4 s = *(const float4*)base;
#pragma unroll
    for (int ks = 1; ks < 4; ++ks) {
        float4 t = *(const float4*)(base + (size_t)ks * V_ * K_);
        s.x += t.x; s.y += t.y; s.z += t.z; s.w += t.w;
    }
    u16* dst = (z < 4 ? GXE : GYE) + (size_t)(z & 3) * V_ * K_ + r;
    ushort4 o;
    o.x = f2bf(s.x); o.y = f2bf(s.y); o.z = f2bf(s.z); o.w = f2bf(s.w);
    *(ushort4*)dst = o;
}

// ---- k_spec: spec partial = evT[:, vchunk] @ (mass*x)[vchunk, :] ------------
// x read row-major; mass-scaled transpose built in LDS (no XMT buffer).
__global__ __launch_bounds__(256, 2) void k_spec(const u16* __restrict__ evT,
                                                 const u16* __restrict__ xb,
                                                 const float* __restrict__ mass,
                                                 float* __restrict__ SP) {
    __shared__ alignas(16) u16 As[128 * 64];   // evT tile [k][64v]
    __shared__ alignas(16) u16 Bs[128 * 64];   // (mass*x)^T [c][64v]
    int vc = blockIdx.x, b = blockIdx.y;
    const int tid = threadIdx.x, lane = tid & 63, wave = tid >> 6;
    const int q = lane >> 4, m = lane & 15;
    const int r8 = lane >> 3, s8 = lane & 7;
    const u16* Ab = evT + (size_t)b * K_ * V_ + vc * 64;
#pragma unroll
    for (int c2 = 0; c2 < 4; ++c2) {
        int row0 = wave * 32 + c2 * 8;
        int row = row0 + r8;
        gl_lds16(Ab + (size_t)row * V_ + ((s8 ^ (row & 7)) << 3), As + row0 * 64);
    }
    {
        int v = tid & 63, cg = tid >> 6;
        const u16* xrow = xb + ((size_t)b * V_ + vc * 64 + v) * C_;
        float ms = mass[(size_t)b * V_ + vc * 64 + v];
#pragma unroll
        for (int j = 0; j < 4; ++j) {
            short8 d = *(const short8*)(xrow + cg * 32 + j * 8);
#pragma unroll
            for (int e2 = 0; e2 < 8; ++e2) {
                int c = cg * 32 + j * 8 + e2;
                Bs[c * 64 + (((v >> 3) ^ (c & 7)) << 3) + (v & 7)] =
                    f2bf(bf2f((u16)d[e2]) * ms);
            }
        }
    }
    __syncthreads();
    f32x4 acc[4][4];
#pragma unroll
    for (int i = 0; i < 4; ++i)
#pragma unroll
        for (int j = 0; j < 4; ++j) acc[i][j] = {0.f, 0.f, 0.f, 0.f};
    const int rwv = wave >> 1, cwv = wave & 1;
#pragma unroll
    for (int s = 0; s < 2; ++s) {
        short8 a[4], bb[4];
#pragma unroll
        for (int rt = 0; rt < 4; ++rt) {
            int row = rwv * 64 + rt * 16 + m;
            a[rt] = *(const short8*)(As + row * 64 + (((s * 4 + q) ^ (row & 7)) << 3));
        }
#pragma unroll
        for (int ct = 0; ct < 4; ++ct) {
            int c = cwv * 64 + ct * 16 + m;
            bb[ct] = *(const short8*)(Bs + c * 64 + (((s * 4 + q) ^ (c & 7)) << 3));
        }
#pragma unroll
        for (int rt = 0; rt < 4; ++rt)
#pragma unroll
            for (int ct = 0; ct < 4; ++ct)
                acc[rt][ct] = mfma16(a[rt], bb[ct], acc[rt][ct]);
    }
    float* outp = SP + ((size_t)b * 64 + vc) * (K_ * C_);
#pragma unroll
    for (int rt = 0; rt < 4; ++rt)
#pragma unroll
        for (int ct = 0; ct < 4; ++ct)
#pragma unroll
            for (int r = 0; r < 4; ++r) {
                int row = rwv * 64 + rt * 16 + q * 4 + r;
                int col = cwv * 64 + ct * 16 + m;
                outp[(size_t)row * C_ + col] = acc[rt][ct][r];
            }
}

// ---- k_reduce: sum 64 spec partials, apply exp(-evals*t), write Y^T ---------
__global__ void k_reduce(const float* __restrict__ SP, const float* __restrict__ evals,
                         const float* __restrict__ tvec, u16* __restrict__ yt) {
    int idx = blockIdx.x * 256 + threadIdx.x;  // B*K*C
    int c = idx & 127, k = (idx >> 7) & 127, b = idx >> 14;
    float ti = fmaxf(tvec[c], 1e-8f);
    float coef = expf(-evals[b * 128 + k] * ti);
    const float* p = SP + (size_t)b * 64 * (K_ * C_) + k * C_ + c;
    float s = 0.f;
#pragma unroll
    for (int j = 0; j < 64; ++j) s += p[(size_t)j * (K_ * C_)];
    yt[((size_t)b * C_ + c) * K_ + k] = f2bf(coef * s);
}

// ---- k_tile: fused per-32-row-tile pipeline ---------------------------------
// xd/gx/gy = {EVB,GXE,GYE}@Y; gfeat = tanh(gx*br+gy*bi); 3-layer MLP; residual.
__global__ __launch_bounds__(256, 2) void k_tile(
    const u16* __restrict__ evb, const u16* __restrict__ gxe,
    const u16* __restrict__ gye, const u16* __restrict__ yt,
    const u16* __restrict__ art, const u16* __restrict__ ait,
    const u16* __restrict__ w0t, const u16* __restrict__ w1t,
    const u16* __restrict__ w2t, const float* __restrict__ b0,
    const float* __restrict__ b1, const float* __restrict__ b2,
    float* __restrict__ x32, u16* __restrict__ xbg) {
    __shared__ alignas(16) u16 smem[32768];     // 64 KiB
    u16* RA  = smem;            // 32 KB: Y -> ART/AIT halves -> W chunks
    u16* RB  = smem + 16384;    // 8 KB: A-stage -> gfeat
    u16* RC0 = smem + 20480;    // 8 KB: xd -> h1
    u16* RC1 = smem + 24576;    // 8 KB: gx -> xb stage
    u16* RC2 = smem + 28672;    // 8 KB: gy -> h0
    const int tid = threadIdx.x, lane = tid & 63, wave = tid >> 6;
    const int q = lane >> 4, m = lane & 15;
    const int rw = wave >> 1, cw = wave & 1;
    const int r4 = lane >> 4, h4 = (lane >> 3) & 1, s4 = lane & 7;
    const int r8 = lane >> 3, s8 = lane & 7;
    const int mt = blockIdx.x, b = blockIdx.y;
    const size_t boff = ((size_t)b * V_ + mt * 32) * (size_t)C_;

    // stage Y [128c][128k] -> RA
    {
        const u16* Y = yt + (size_t)b * C_ * K_;
#pragma unroll
        for (int c2 = 0; c2 < 8; ++c2) {
            int row0 = wave * 32 + c2 * 4;
            int row = row0 + r4;
            gl_lds16(Y + (size_t)row * 128 + h4 * 64 + ((s4 ^ (row & 7)) << 3),
                     RA + row0 * 128);
        }
    }
    // phase 1: xd, gx, gy  (32x128 each, K=128)
#pragma unroll 1
    for (int p = 0; p < 3; ++p) {
        __syncthreads();
        const u16* Asrc = (p == 0 ? evb : p == 1 ? gxe : gye) + boff;
#pragma unroll
        for (int c2 = 0; c2 < 2; ++c2) {
            int row0 = wave * 8 + c2 * 4;
            int row = row0 + r4;
            gl_lds16(Asrc + (size_t)row * 128 + h4 * 64 + ((s4 ^ (row & 7)) << 3),
                     RB + row0 * 128);
        }
        __syncthreads();
        f32x4 acc[4];
#pragma unroll
        for (int j = 0; j < 4; ++j) acc[j] = {0.f, 0.f, 0.f, 0.f};
#pragma unroll
        for (int s = 0; s < 4; ++s) {
            int ar = rw * 16 + m;
            short8 a = *(const short8*)(RB + ar * 128 + ((s >> 1) << 6) +
                                        ((((s & 1) * 4 + q) ^ (ar & 7)) << 3));
#pragma unroll
            for (int ct = 0; ct < 4; ++ct) {
                int c = cw * 64 + ct * 16 + m;
                short8 bb = *(const short8*)(RA + c * 128 + ((s >> 1) << 6) +
                                             ((((s & 1) * 4 + q) ^ (c & 7)) << 3));
                acc[ct] = mfma16(a, bb, acc[ct]);
            }
        }
        u16* dst = (p == 0 ? RC0 : p == 1 ? RC1 : RC2);
#pragma unroll
        for (int ct = 0; ct < 4; ++ct)
#pragma unroll
            for (int r = 0; r < 4; ++r) {
                int row = rw * 16 + q * 4 + r;
                int col = cw * 64 + ct * 16 + m;
                dst[poff(row, col)] = f2bf(acc[ct][r]);
            }
    }
    __syncthreads();
    // phase 2: complex-linear + tanh -> gfeat in RB
#pragma unroll 1
    for (int h = 0; h < 2; ++h) {
        if (h) __syncthreads();
#pragma unroll
        for (int c2 = 0; c2 < 4; ++c2) {
            int row0 = wave * 16 + c2 * 4;
            int row = row0 + r4;
            size_t so = (size_t)(h * 64 + row) * 128 + h4 * 64 + ((s4 ^ (row & 7)) << 3);
            gl_lds16(art + so, RA + row0 * 128);
            gl_lds16(ait + so, RA + 8192 + row0 * 128);
        }
        __syncthreads();
        f32x4 br[2], bi[2];
#pragma unroll
        for (int j = 0; j < 2; ++j) { br[j] = {0.f, 0.f, 0.f, 0.f}; bi[j] = {0.f, 0.f, 0.f, 0.f}; }
#pragma unroll
        for (int s = 0; s < 4; ++s) {
            int ar = rw * 16 + m;
            int ao = ar * 128 + ((s >> 1) << 6) + ((((s & 1) * 4 + q) ^ (ar & 7)) << 3);
            short8 ax = *(const short8*)(RC1 + ao);
            short8 ay = *(const short8*)(RC2 + ao);
#pragma unroll
            for (int ct = 0; ct < 2; ++ct) {
                int n = cw * 32 + ct * 16 + m;
                int bo = n * 128 + ((s >> 1) << 6) + ((((s & 1) * 4 + q) ^ (n & 7)) << 3);
                short8 bre = *(const short8*)(RA + bo);
                short8 bim = *(const short8*)(RA + 8192 + bo);
                short8 bimn;
#pragma unroll
                for (int j = 0; j < 8; ++j) bimn[j] = bim[j] ^ (short)0x8000;
                br[ct] = mfma16(ax, bre, br[ct]);
                br[ct] = mfma16(ay, bimn, br[ct]);
                bi[ct] = mfma16(ay, bre, bi[ct]);
                bi[ct] = mfma16(ax, bim, bi[ct]);
            }
        }
#pragma unroll
        for (int ct = 0; ct < 2; ++ct)
#pragma unroll
            for (int r = 0; r < 4; ++r) {
                int row = rw * 16 + q * 4 + r;
                int col = h * 64 + cw * 32 + ct * 16 + m;
                int off = poff(row, col);
                float g1 = bf2f(RC1[off]), g2 = bf2f(RC2[off]);
                RB[off] = f2bf(tanhf(g1 * br[ct][r] + g2 * bi[ct][r]));
            }
    }
    __syncthreads();
    // phase 3: MLP. stage x tile -> RC1
#pragma unroll
    for (int c2 = 0; c2 < 2; ++c2) {
        int row0 = wave * 8 + c2 * 4;
        int row = row0 + r4;
        gl_lds16(xbg + boff + (size_t)row * 128 + h4 * 64 + ((s4 ^ (row & 7)) << 3),
                 RC1 + row0 * 128);
    }
    f32x4 acc0[4];
#pragma unroll
    for (int j = 0; j < 4; ++j) acc0[j] = {0.f, 0.f, 0.f, 0.f};
#pragma unroll 1
    for (int kc = 0; kc < 6; ++kc) {
        if (kc) __syncthreads();
#pragma unroll
        for (int c2 = 0; c2 < 4; ++c2) {
            int row0 = wave * 32 + c2 * 8;
            int row = row0 + r8;
            gl_lds16(w0t + (size_t)row * 384 + kc * 64 + ((s8 ^ (row & 7)) << 3),
                     RA + row0 * 64);
        }
        __syncthreads();
        const u16* Ab = (kc < 2) ? RC1 : (kc < 4) ? RC0 : RB;
        int half = kc & 1;
#pragma unroll
        for (int s = 0; s < 2; ++s) {
            int ar = rw * 16 + m;
            short8 a = *(const short8*)(Ab + ar * 128 + (half << 6) +
                                        (((s * 4 + q) ^ (ar & 7)) << 3));
#pragma unroll
            for (int ct = 0; ct < 4; ++ct) {
                int n = cw * 64 + ct * 16 + m;
                short8 bb = *(const short8*)(RA + n * 64 + (((s * 4 + q) ^ (n & 7)) << 3));
                acc0[ct] = mfma16(a, bb, acc0[ct]);
            }
        }
    }
    __syncthreads();
    // h0 = relu(acc0 + b0) -> RC2
#pragma unroll
    for (int ct = 0; ct < 4; ++ct)
#pragma unroll
        for (int r = 0; r < 4; ++r) {
            int row = rw * 16 + q * 4 + r;
            int col = cw * 64 + ct * 16 + m;
            RC2[poff(row, col)] = f2bf(fmaxf(acc0[ct][r] + b0[col], 0.f));
        }
    __syncthreads();
    // layer 1: h1 = relu(h0 @ W1 + b1) -> RC0
    f32x4 acc1[4];
#pragma unroll
    for (int j = 0; j < 4; ++j) acc1[j] = {0.f, 0.f, 0.f, 0.f};
#pragma unroll 1
    for (int kc = 0; kc < 2; ++kc) {
        if (kc) __syncthreads();
#pragma unroll
        for (int c2 = 0; c2 < 4; ++c2) {
            int row0 = wave * 32 + c2 * 8;
            int row = row0 + r8;
            gl_lds16(w1t + (size_t)row * 128 + kc * 64 + ((s8 ^ (row & 7)) << 3),
                     RA + row0 * 64);
        }
        __syncthreads();
#pragma unroll
        for (int s = 0; s < 2; ++s) {
            int ar = rw * 16 + m;
            short8 a = *(const short8*)(RC2 + ar * 128 + (kc << 6) +
                                        (((s * 4 + q) ^ (ar & 7)) << 3));
#pragma unroll
            for (int ct = 0; ct < 4; ++ct) {
                int n = cw * 64 + ct * 16 + m;
                short8 bb = *(const short8*)(RA + n * 64 + (((s * 4 + q) ^ (n & 7)) << 3));
                acc1[ct] = mfma16(a, bb, acc1[ct]);
            }
        }
    }
    __syncthreads();
#pragma unroll
    for (int ct = 0; ct < 4; ++ct)
#pragma unroll
        for (int r = 0; r < 4; ++r) {
            int row = rw * 16 + q * 4 + r;
            int col = cw * 64 + ct * 16 + m;
            RC0[poff(row, col)] = f2bf(fmaxf(acc1[ct][r] + b1[col], 0.f));
        }
    __syncthreads();
    // layer 2 + residual
    f32x4 acc2[4];
#pragma unroll
    for (int j = 0; j < 4; ++j) acc2[j] = {0.f, 0.f, 0.f, 0.f};
#pragma unroll 1
    for (int kc = 0; kc < 2; ++kc) {
        if (kc) __syncthreads();
#pragma unroll
        for (int c2 = 0; c2 < 4; ++c2) {
            int row0 = wave * 32 + c2 * 8;
            int row = row0 + r8;
            gl_lds16(w2t + (size_t)row * 128 + kc * 64 + ((s8 ^ (row & 7)) << 3),
                     RA + row0 * 64);
        }
        __syncthreads();
#pragma unroll
        for (int s = 0; s < 2; ++s) {
            int ar = rw * 16 + m;
            short8 a = *(const short8*)(RC0 + ar * 128 + (kc << 6) +
                                        (((s * 4 + q) ^ (ar & 7)) << 3));
#pragma unroll
            for (int ct = 0; ct < 4; ++ct) {
                int n = cw * 64 + ct * 16 + m;
                short8 bb = *(const short8*)(RA + n * 64 + (((s * 4 + q) ^ (n & 7)) << 3));
                acc2[ct] = mfma16(a, bb, acc2[ct]);
            }
        }
    }
#pragma unroll
    for (int ct = 0; ct < 4; ++ct)
#pragma unroll
        for (int r = 0; r < 4; ++r) {
            int row = rw * 16 + q * 4 + r;
            int col = cw * 64 + ct * 16 + m;
            size_t idx = boff + (size_t)row * C_ + col;
            float v = x32[idx] + acc2[ct][r] + b2[col];
            x32[idx] = v;
            xbg[idx] = f2bf(v);
        }
}

// ---- k_final: out = x @ Wl + bl (fp32 out) ----------------------------------
__global__ __launch_bounds__(256, 2) void k_final(const u16* __restrict__ xb,
                                                  const u16* __restrict__ wlt,
                                                  const float* __restrict__ bl,
                                                  float* __restrict__ out) {
    __shared__ alignas(16) u16 As[128 * 64];
    __shared__ alignas(16) u16 Bs[128 * 64];
    int mt = blockIdx.x, b = blockIdx.y;
    size_t boff = (size_t)b * V_ * C_ + (size_t)mt * 128 * C_;
    f32x4 acc[4][4];
#pragma unroll
    for (int i = 0; i < 4; ++i)
#pragma unroll
        for (int j = 0; j < 4; ++j) acc[i][j] = {0.f, 0.f, 0.f, 0.f};
    gemm_core<4>(xb + boff, C_, wlt, C_, 2, acc, As, Bs);
    int lane = threadIdx.x & 63, wave = threadIdx.x >> 6;
    int rb = (wave >> 1) * 64, cb = (wave & 1) * 64, q = lane >> 4, m = lane & 15;
#pragma unroll
    for (int rt = 0; rt < 4; ++rt)
#pragma unroll
        for (int ct = 0; ct < 4; ++ct)
#pragma unroll
            for (int r = 0; r < 4; ++r) {
                int row = rb + rt * 16 + q * 4 + r;
                int col = cb + ct * 16 + m;
                out[boff + (size_t)row * C_ + col] = acc[rt][ct][r] + bl[col];
            }
}

extern "C" void kernel_launch(void* const* d_in, const int* in_sizes, int n_in,
                              void* d_out, int out_size, void* d_ws,
                              size_t ws_size, hipStream_t stream) {
    (void)in_sizes; (void)n_in; (void)out_size; (void)ws_size;
    const float* x_in  = (const float*)d_in[0];
    const float* mass  = (const float*)d_in[1];
    const float* evals = (const float*)d_in[2];
    const float* evecs = (const float*)d_in[3];
    const float* gradX = (const float*)d_in[4];
    const float* gradY = (const float*)d_in[5];
    const float* Wf    = (const float*)d_in[6];
    const float* bfv   = (const float*)d_in[7];
    const float* Wl    = (const float*)d_in[8];
    const float* bl    = (const float*)d_in[9];
    const float* tv    = (const float*)d_in[10];
    const float* Are   = (const float*)d_in[11];
    const float* Aim   = (const float*)d_in[12];
    const float* W0    = (const float*)d_in[13];
    const float* b0    = (const float*)d_in[14];
    const float* W1    = (const float*)d_in[15];
    const float* b1    = (const float*)d_in[16];
    const float* W2    = (const float*)d_in[17];
    const float* b2    = (const float*)d_in[18];
    float* out = (float*)d_out;

    char* wsb = (char*)d_ws;
    size_t o = 0;
    auto take = [&](size_t bytes) -> void* {
        void* p = wsb + o;
        o += (bytes + 255) & ~(size_t)255;
        return p;
    };
    float* X32 = (float*)take((size_t)B_ * V_ * C_ * 4);
    u16* XB    = (u16*)take((size_t)B_ * V_ * C_ * 2);
    u16* EVT   = (u16*)take((size_t)B_ * V_ * K_ * 2);
    u16* EVB   = (u16*)take((size_t)B_ * V_ * K_ * 2);
    u16* GXE   = (u16*)take((size_t)B_ * V_ * K_ * 2);
    u16* GYE   = (u16*)take((size_t)B_ * V_ * K_ * 2);
    float* GP  = (float*)take((size_t)8 * 4 * V_ * K_ * 4);   // 67 MB
    float* SP  = (float*)take((size_t)B_ * 64 * K_ * C_ * 4); // 16.8 MB
    u16* YT    = (u16*)take((size_t)B_ * K_ * C_ * 2);
    u16* ART   = (u16*)take((size_t)4 * C_ * C_ * 2);
    u16* AIT   = (u16*)take((size_t)4 * C_ * C_ * 2);
    u16* W0T   = (u16*)take((size_t)4 * 384 * C_ * 2);
    u16* W1T   = (u16*)take((size_t)4 * C_ * C_ * 2);
    u16* W2T   = (u16*)take((size_t)4 * C_ * C_ * 2);
    u16* WLT   = (u16*)take((size_t)C_ * C_ * 2);

    k_prep<<<dim3(116), 256, 0, stream>>>(Are, Aim, W0, W1, W2, Wl,
                                          ART, AIT, W0T, W1T, W2T, WLT);
    k_evt<<<dim3(64, 2, 4), 256, 0, stream>>>(evecs, EVT, EVB);
    k_init<<<dim3(8192), 256, 0, stream>>>(x_in, Wf, bfv, X32, XB);
    k_gxe<<<dim3(64, 4, 8), 256, 0, stream>>>(gradX, gradY, EVT, GP);
    k_gxered<<<dim3(4096), 256, 0, stream>>>(GP, GXE, GYE);

    for (int i = 0; i < 4; ++i) {
        k_spec<<<dim3(64, 4), 256, 0, stream>>>(EVT, XB, mass, SP);
        k_reduce<<<dim3(256), 256, 0, stream>>>(SP, evals, tv + i * 128, YT);
        k_tile<<<dim3(128, 4), 256, 0, stream>>>(
            EVB, GXE, GYE, YT, ART + i * 16384, AIT + i * 16384,
            W0T + i * 49152, W1T + i * 16384, W2T + i * 16384,
            b0 + i * 128, b1 + i * 128, b2 + i * 128, X32, XB);
    }
    k_final<<<dim3(32, 4), 256, 0, stream>>>(XB, WLT, bl, out);
}